// Round 5
// baseline (1140.625 us; speedup 1.0000x reference)
//
#include <hip/hip_runtime.h>

typedef unsigned short u16;
typedef unsigned int u32;
typedef __attribute__((ext_vector_type(4))) float f32x4;
typedef __attribute__((ext_vector_type(8))) short short8;
typedef __attribute__((ext_vector_type(4))) short short4v;

#define HIDDEN 2048
#define NHEADS 16
#define KEYDIM 1024
#define VALDIM 2048
#define HEADK 64
#define HEADV 128
#define NBATCH 8
#define SEQ 4096
#define NTOK (NBATCH * SEQ)

__device__ __forceinline__ u16 f2bf(float f) {
  union { float f; u32 u; } c; c.f = f;
  u32 r = c.u + 0x7FFFu + ((c.u >> 16) & 1u);
  return (u16)(r >> 16);
}
__device__ __forceinline__ float bf2f(u16 h) {
  union { u32 u; float f; } c; c.u = ((u32)h) << 16;
  return c.f;
}

// ---------------- weight cast f32 -> bf16 ----------------
__global__ __launch_bounds__(256) void cast_bf16_k(const float* __restrict__ in,
                                                   u16* __restrict__ out, int n4) {
  int i = blockIdx.x * blockDim.x + threadIdx.x;
  if (i >= n4) return;
  f32x4 v = *(const f32x4*)(in + (size_t)i * 4);
  short4v o;
  o[0] = (short)f2bf(v[0]); o[1] = (short)f2bf(v[1]);
  o[2] = (short)f2bf(v[2]); o[3] = (short)f2bf(v[3]);
  *(short4v*)(out + (size_t)i * 4) = o;
}

// ---------------- K1: RMSNorm(hidden) -> bf16 ----------------
__global__ __launch_bounds__(256) void rmsnorm_cast_k(const float* __restrict__ x,
                                                      const float* __restrict__ w,
                                                      u16* __restrict__ xb) {
  int r = blockIdx.x;
  int tid = threadIdx.x;
  const float* xp = x + (size_t)r * HIDDEN + tid * 8;
  f32x4 v0 = *(const f32x4*)xp;
  f32x4 v1 = *(const f32x4*)(xp + 4);
  float ss = v0[0]*v0[0]+v0[1]*v0[1]+v0[2]*v0[2]+v0[3]*v0[3]
           + v1[0]*v1[0]+v1[1]*v1[1]+v1[2]*v1[2]+v1[3]*v1[3];
  #pragma unroll
  for (int m = 32; m >= 1; m >>= 1) ss += __shfl_xor(ss, m);
  __shared__ float red[4];
  if ((tid & 63) == 0) red[tid >> 6] = ss;
  __syncthreads();
  float tot = red[0] + red[1] + red[2] + red[3];
  float inv = rsqrtf(tot * (1.0f / HIDDEN) + 1e-5f);
  const float* wp = w + tid * 8;
  f32x4 w0 = *(const f32x4*)wp;
  f32x4 w1 = *(const f32x4*)(wp + 4);
  short8 o;
  o[0] = (short)f2bf(v0[0] * inv * w0[0]);
  o[1] = (short)f2bf(v0[1] * inv * w0[1]);
  o[2] = (short)f2bf(v0[2] * inv * w0[2]);
  o[3] = (short)f2bf(v0[3] * inv * w0[3]);
  o[4] = (short)f2bf(v1[0] * inv * w1[0]);
  o[5] = (short)f2bf(v1[1] * inv * w1[1]);
  o[6] = (short)f2bf(v1[2] * inv * w1[2]);
  o[7] = (short)f2bf(v1[3] * inv * w1[3]);
  *(short8*)(xb + (size_t)r * HIDDEN + tid * 8) = o;
}

// ------- 128x128 GEMM, BK=32, 256 thr, 3-buffer ring, 3 blocks/CU -------
// C[M,N] = A[M,K] @ B[N,K]^T, bf16 in. MODE: 0 bf16 store, 1 sigmoid f32, 2 f32 RMW *=
// LDS: 3 x 16 KB ring (per buffer: A 128x32 bf16 = 8 KB, B = 8 KB).
// Per K-tile (ONE barrier, ONE waitcnt):
//   { 8x ds_read(buf c%3); STAGE(c+2 -> buf (c+2)%3);
//     s_waitcnt vmcnt(4) lgkmcnt(0); s_barrier; 16x MFMA }
// Safety: lgkm(0) pre-barrier => all waves' reads of buf X complete before any
// wave's post-barrier iteration can DMA into X (X is re-targeted 2 tiles later,
// i.e. >= 1 barrier after its readers drained).  vmcnt(4) leaves only the
// just-issued STAGE(c+2) (4 loads/wave) in flight => STAGE(c+1) landed for the
// next iteration's reads.  Tail: vmcnt(0) when no stage issued, nothing at last.
// 48 KiB LDS + <=168 VGPR => 3 blocks/CU: independent barrier groups overlap
// each other's stalls (the m97-structure's missing ingredient in R2-R4).

__device__ __forceinline__ void gload16(const u16* g, u16* l) {
  __builtin_amdgcn_global_load_lds((const __attribute__((address_space(1))) void*)g,
                                   (__attribute__((address_space(3))) void*)l, 16, 0, 0);
}

template <int MODE>
__global__ __launch_bounds__(256, 3) void gemm128r_k(const u16* __restrict__ A,
                                                     const u16* __restrict__ Bw,
                                                     void* __restrict__ Cptr,
                                                     int M, int N, int K) {
  extern __shared__ u16 lds[];
  const int tid = threadIdx.x;
  const int wid = tid >> 6;
  const int wm = wid >> 1;          // 0..1 (M half: 64 rows)
  const int wn = wid & 1;           // 0..1 (N half: 64 cols)
  const int l = tid & 63;
  const int lr = l & 15;
  const int kq = l >> 4;

  // XCD-aware swizzle + N-tile-fastest (gridDim.x % 8 == 0 for all shapes here)
  const int ntn = N >> 7;
  const int per = gridDim.x >> 3;
  const int b = blockIdx.x;
  const int sidx = (b & 7) * per + (b >> 3);
  const int mt = sidx / ntn;
  const int nt = sidx - mt * ntn;

  const u16* Ag = A + (size_t)(mt * 128) * K;
  const u16* Bg = Bw + (size_t)(nt * 128) * K;

  // staging: per instr 256 thr x 16 B = 64 rows x 64 B
  const int srow = tid >> 2;                              // 0..63
  const int kel = (((tid & 3) ^ ((tid >> 3) & 3)) << 3);  // pre-swizzled source chunk

  // buffer bi base = bi*8192 u16;  A [0,4096), B [4096,8192)
#define STAGE(c, bi)                                                  \
  do {                                                                \
    const u16* _sa = Ag + (size_t)srow * K + ((c) << 5) + kel;        \
    u16* _d = lds + (bi) * 8192 + tid * 8;                            \
    gload16(_sa, _d);                                                 \
    gload16(_sa + (size_t)64 * K, _d + 2048);                         \
    const u16* _sb = Bg + (size_t)srow * K + ((c) << 5) + kel;        \
    gload16(_sb, _d + 4096);                                          \
    gload16(_sb + (size_t)64 * K, _d + 6144);                         \
  } while (0)

  // loop-invariant swizzled fragment offsets (u16 units)
  int aoff[4], boff[4];
  #pragma unroll
  for (int mi = 0; mi < 4; ++mi) {
    int R = wm * 64 + mi * 16 + lr;
    aoff[mi] = R * 32 + ((kq ^ ((R >> 1) & 3)) << 3);
  }
  #pragma unroll
  for (int n = 0; n < 4; ++n) {
    int R = wn * 64 + n * 16 + lr;
    boff[n] = 4096 + R * 32 + ((kq ^ ((R >> 1) & 3)) << 3);
  }

  f32x4 acc[4][4] = {};

  // ---- prologue ----
  STAGE(0, 0);
  STAGE(1, 1);
  asm volatile("s_waitcnt vmcnt(4)" ::: "memory");   // tile 0 landed (all but newest 4)
  __builtin_amdgcn_s_barrier();

  const int NT = K >> 5;
  int cur = 0, nxt = 1, stg = 2;
  #pragma unroll 1
  for (int c = 0; c < NT; ++c) {
    const u16* bufT = lds + cur * 8192;
    short8 afr[4], bfr[4];
    #pragma unroll
    for (int mi = 0; mi < 4; ++mi) afr[mi] = *(const short8*)(bufT + aoff[mi]);
    #pragma unroll
    for (int n = 0; n < 4; ++n)   bfr[n] = *(const short8*)(bufT + boff[n]);

    if (c + 2 < NT) {
      STAGE(c + 2, stg);
      asm volatile("s_waitcnt vmcnt(4) lgkmcnt(0)" ::: "memory");
    } else if (c + 1 < NT) {
      asm volatile("s_waitcnt vmcnt(0) lgkmcnt(0)" ::: "memory");
    } else {
      asm volatile("s_waitcnt lgkmcnt(0)" ::: "memory");
    }
    __builtin_amdgcn_s_barrier();

    __builtin_amdgcn_s_setprio(1);
    #pragma unroll
    for (int mi = 0; mi < 4; ++mi) {
      #pragma unroll
      for (int n = 0; n < 4; ++n)
        acc[mi][n] = __builtin_amdgcn_mfma_f32_16x16x32_bf16(afr[mi], bfr[n], acc[mi][n], 0, 0, 0);
    }
    __builtin_amdgcn_s_setprio(0);

    int t = cur; cur = nxt; nxt = stg; stg = t;
  }
#undef STAGE

  // ---- epilogue ----
  const int rowB = mt * 128 + wm * 64 + kq * 4;
  const int colB = nt * 128 + wn * 64 + lr;
  #pragma unroll
  for (int m = 0; m < 4; ++m) {
    #pragma unroll
    for (int n = 0; n < 4; ++n) {
      #pragma unroll
      for (int j = 0; j < 4; ++j) {
        int row = rowB + m * 16 + j;
        int col = colB + n * 16;
        size_t idx = (size_t)row * N + col;
        float v = acc[m][n][j];
        if constexpr (MODE == 0) {
          ((u16*)Cptr)[idx] = f2bf(v);
        } else if constexpr (MODE == 1) {
          ((float*)Cptr)[idx] = 1.0f / (1.0f + __expf(-v));
        } else {
          float* O = (float*)Cptr;
          O[idx] = O[idx] * v;
        }
      }
    }
  }
}

// ---------------- K3: L2-normalize(q head) @ S[b,h] -> RMSNorm -> bf16 o_mid ----------------
__global__ __launch_bounds__(256) void glaread_k(const u16* __restrict__ q,
                                                 const float* __restrict__ S,
                                                 const float* __restrict__ vw,
                                                 u16* __restrict__ omid) {
  int bh = blockIdx.x;             // b*16 + h
  int b = bh >> 4, h = bh & 15;
  int tid = threadIdx.x;
  int w = tid >> 6, l = tid & 63;
  int lr = l & 15, kq = l >> 4;

  const float* Sp = S + (size_t)bh * HEADK * HEADV;
  short8 bfrag[8][2];
  #pragma unroll
  for (int n = 0; n < 8; ++n) {
    #pragma unroll
    for (int s = 0; s < 2; ++s) {
      #pragma unroll
      for (int i = 0; i < 8; ++i)
        bfrag[n][s][i] =
            (short)f2bf(Sp[(size_t)(s * 32 + kq * 8 + i) * HEADV + n * 16 + lr]);
    }
  }
  float vwn[8];
  #pragma unroll
  for (int n = 0; n < 8; ++n) vwn[n] = vw[n * 16 + lr];

  #pragma unroll 1
  for (int it = 0; it < 8; ++it) {
    int t0 = blockIdx.y * 512 + it * 64 + w * 16;
    const u16* qp = q + (size_t)(b * SEQ + t0 + lr) * KEYDIM + h * HEADK;
    short8 a0 = *(const short8*)(qp + kq * 8);
    short8 a1 = *(const short8*)(qp + 32 + kq * 8);

    float ss = 0.f;
    #pragma unroll
    for (int i = 0; i < 8; ++i) {
      float x0 = bf2f((u16)a0[i]), x1 = bf2f((u16)a1[i]);
      ss += x0 * x0 + x1 * x1;
    }
    ss += __shfl_xor(ss, 16);
    ss += __shfl_xor(ss, 32);
    float sc = 1.0f / fmaxf(sqrtf(ss), 1e-12f);

    short8 an0, an1;
    #pragma unroll
    for (int i = 0; i < 8; ++i) {
      an0[i] = (short)f2bf(bf2f((u16)a0[i]) * sc);
      an1[i] = (short)f2bf(bf2f((u16)a1[i]) * sc);
    }

    f32x4 acc[8] = {};
    #pragma unroll
    for (int n = 0; n < 8; ++n) {
      acc[n] = __builtin_amdgcn_mfma_f32_16x16x32_bf16(an0, bfrag[n][0], acc[n], 0, 0, 0);
      acc[n] = __builtin_amdgcn_mfma_f32_16x16x32_bf16(an1, bfrag[n][1], acc[n], 0, 0, 0);
    }

    float part[4] = {0.f, 0.f, 0.f, 0.f};
    #pragma unroll
    for (int n = 0; n < 8; ++n) {
      #pragma unroll
      for (int j = 0; j < 4; ++j) part[j] += acc[n][j] * acc[n][j];
    }
    #pragma unroll
    for (int msk = 1; msk <= 8; msk <<= 1) {
      #pragma unroll
      for (int j = 0; j < 4; ++j) part[j] += __shfl_xor(part[j], msk);
    }
    #pragma unroll
    for (int j = 0; j < 4; ++j) {
      float inv = rsqrtf(part[j] * (1.0f / HEADV) + 1e-5f);
      int tok = t0 + kq * 4 + j;
      u16* op = omid + (size_t)(b * SEQ + tok) * VALDIM + h * HEADV;
      #pragma unroll
      for (int n = 0; n < 8; ++n)
        op[n * 16 + lr] = f2bf(acc[n][j] * inv * vwn[n]);
    }
  }
}

extern "C" void kernel_launch(void* const* d_in, const int* in_sizes, int n_in,
                              void* d_out, int out_size, void* d_ws, size_t ws_size,
                              hipStream_t stream) {
  const float* hs = (const float*)d_in[0];   // (8,4096,2048)
  const float* S  = (const float*)d_in[1];   // (8,16,64,128)
  const float* nw = (const float*)d_in[2];   // (2048)
  const float* qw = (const float*)d_in[3];   // (1024,2048)
  const float* vw = (const float*)d_in[4];   // (128)
  const float* ow = (const float*)d_in[5];   // (2048,2048)
  const float* gw = (const float*)d_in[6];   // (2048,2048)
  float* out = (float*)d_out;

  u16* xb   = (u16*)d_ws;                             // NTOK*2048 bf16
  u16* q    = xb + (size_t)NTOK * HIDDEN;             // NTOK*1024 bf16
  u16* qwb  = q + (size_t)NTOK * KEYDIM;              // 1024*2048
  u16* owb  = qwb + (size_t)KEYDIM * HIDDEN;          // 2048*2048
  u16* gwb  = owb + (size_t)HIDDEN * VALDIM;          // 2048*2048
  u16* omid = xb;  // reuse xb after gate GEMM has consumed it

  const size_t LDSB = 49152;  // 3 x 16 KB ring

  // weight casts
  cast_bf16_k<<<(KEYDIM * HIDDEN / 4 + 255) / 256, 256, 0, stream>>>(qw, qwb, KEYDIM * HIDDEN / 4);
  cast_bf16_k<<<(HIDDEN * VALDIM / 4 + 255) / 256, 256, 0, stream>>>(ow, owb, HIDDEN * VALDIM / 4);
  cast_bf16_k<<<(HIDDEN * HIDDEN / 4 + 255) / 256, 256, 0, stream>>>(gw, gwb, HIDDEN * HIDDEN / 4);

  // x = rmsnorm(hidden) -> bf16
  rmsnorm_cast_k<<<NTOK, 256, 0, stream>>>(hs, nw, xb);

  // q = x @ q_w^T  (bf16 out)
  gemm128r_k<0><<<dim3((NTOK / 128) * (KEYDIM / 128)), 256, LDSB, stream>>>(xb, qwb, q, NTOK, KEYDIM, HIDDEN);

  // out = sigmoid(x @ gate_w^T)  (f32)
  gemm128r_k<1><<<dim3((NTOK / 128) * (HIDDEN / 128)), 256, LDSB, stream>>>(xb, gwb, out, NTOK, HIDDEN, HIDDEN);

  // o_mid = rmsnorm_v( l2norm(q_head) @ S[b,h] )  (bf16, overwrites xb)
  glaread_k<<<dim3(NBATCH * NHEADS, SEQ / 512), 256, 0, stream>>>(q, S, vw, omid);

  // out *= o_mid @ o_w^T
  gemm128r_k<2><<<dim3((NTOK / 128) * (HIDDEN / 128)), 256, LDSB, stream>>>(omid, owb, out, NTOK, HIDDEN, VALDIM);
}

// Round 6
// 833.367 us; speedup vs baseline: 1.3687x; 1.3687x over previous
//
#include <hip/hip_runtime.h>

typedef unsigned short u16;
typedef unsigned int u32;
typedef __attribute__((ext_vector_type(4))) float f32x4;
typedef __attribute__((ext_vector_type(8))) short short8;
typedef __attribute__((ext_vector_type(4))) short short4v;

#define HIDDEN 2048
#define NHEADS 16
#define KEYDIM 1024
#define VALDIM 2048
#define HEADK 64
#define HEADV 128
#define NBATCH 8
#define SEQ 4096
#define NTOK (NBATCH * SEQ)

__device__ __forceinline__ u16 f2bf(float f) {
  union { float f; u32 u; } c; c.f = f;
  u32 r = c.u + 0x7FFFu + ((c.u >> 16) & 1u);
  return (u16)(r >> 16);
}
__device__ __forceinline__ float bf2f(u16 h) {
  union { u32 u; float f; } c; c.u = ((u32)h) << 16;
  return c.f;
}

// ---------------- weight cast f32 -> bf16 ----------------
__global__ __launch_bounds__(256) void cast_bf16_k(const float* __restrict__ in,
                                                   u16* __restrict__ out, int n4) {
  int i = blockIdx.x * blockDim.x + threadIdx.x;
  if (i >= n4) return;
  f32x4 v = *(const f32x4*)(in + (size_t)i * 4);
  short4v o;
  o[0] = (short)f2bf(v[0]); o[1] = (short)f2bf(v[1]);
  o[2] = (short)f2bf(v[2]); o[3] = (short)f2bf(v[3]);
  *(short4v*)(out + (size_t)i * 4) = o;
}

// ---------------- K1: RMSNorm(hidden) -> bf16 ----------------
__global__ __launch_bounds__(256) void rmsnorm_cast_k(const float* __restrict__ x,
                                                      const float* __restrict__ w,
                                                      u16* __restrict__ xb) {
  int r = blockIdx.x;
  int tid = threadIdx.x;
  const float* xp = x + (size_t)r * HIDDEN + tid * 8;
  f32x4 v0 = *(const f32x4*)xp;
  f32x4 v1 = *(const f32x4*)(xp + 4);
  float ss = v0[0]*v0[0]+v0[1]*v0[1]+v0[2]*v0[2]+v0[3]*v0[3]
           + v1[0]*v1[0]+v1[1]*v1[1]+v1[2]*v1[2]+v1[3]*v1[3];
  #pragma unroll
  for (int m = 32; m >= 1; m >>= 1) ss += __shfl_xor(ss, m);
  __shared__ float red[4];
  if ((tid & 63) == 0) red[tid >> 6] = ss;
  __syncthreads();
  float tot = red[0] + red[1] + red[2] + red[3];
  float inv = rsqrtf(tot * (1.0f / HIDDEN) + 1e-5f);
  const float* wp = w + tid * 8;
  f32x4 w0 = *(const f32x4*)wp;
  f32x4 w1 = *(const f32x4*)(wp + 4);
  short8 o;
  o[0] = (short)f2bf(v0[0] * inv * w0[0]);
  o[1] = (short)f2bf(v0[1] * inv * w0[1]);
  o[2] = (short)f2bf(v0[2] * inv * w0[2]);
  o[3] = (short)f2bf(v0[3] * inv * w0[3]);
  o[4] = (short)f2bf(v1[0] * inv * w1[0]);
  o[5] = (short)f2bf(v1[1] * inv * w1[1]);
  o[6] = (short)f2bf(v1[2] * inv * w1[2]);
  o[7] = (short)f2bf(v1[3] * inv * w1[3]);
  *(short8*)(xb + (size_t)r * HIDDEN + tid * 8) = o;
}

// ---------------- 256x256 GEMM, BK=64, 8-phase schedule (m201 port, UNPINNED) ----------
// C[M,N] = A[M,K] @ B[N,K]^T, bf16 in.
// MODE 0: store bf16.  MODE 1: store sigmoid as bf16.  MODE 2: out = acc * bf2f(Gate[idx]) f32.
// MODE 3: store sigmoid f32.  MODE 4: f32 RMW (out *= acc).   (3/4 = small-ws fallback)
// Barriers are raw s_barrier + pure COMPILER memory fences (no sched_barrier — m141/m218:
// the machine scheduler must stay free; fences only stop cross-barrier LDS-read hoisting).
// Hazard safety: each phase's ds_reads are consumed by that phase's MFMA (lgkm drained
// before phase-end barrier); staged-into half-buffers are re-targeted >=2 barriers after
// their last reader drained. vmcnt(4) at p3/p7 = next K-tile landed, 4 loads in flight.

__device__ __forceinline__ void gload16(const u16* g, u16* l) {
  __builtin_amdgcn_global_load_lds((const __attribute__((address_space(1))) void*)g,
                                   (__attribute__((address_space(3))) void*)l, 16, 0, 0);
}

#define BAR()                                  \
  do {                                         \
    asm volatile("" ::: "memory");             \
    __builtin_amdgcn_s_barrier();              \
    asm volatile("" ::: "memory");             \
  } while (0)

template <int MODE>
__global__ __launch_bounds__(512, 2) void gemm8p_k(const u16* __restrict__ A,
                                                   const u16* __restrict__ Bw,
                                                   void* __restrict__ Cptr,
                                                   const u16* __restrict__ Gate,
                                                   int M, int N, int K) {
  extern __shared__ u16 lds[];
  const int tid = threadIdx.x;
  const int wid = tid >> 6;
  const int wm = wid >> 2;          // 0..1  (M half)
  const int wn = wid & 3;           // 0..3  (N quarter)
  const int l = tid & 63;
  const int lr = l & 15;
  const int kq = l >> 4;

  // XCD-aware swizzle + N-tile-fastest
  const int ntn = N >> 8;
  const int per = gridDim.x >> 3;
  const int b = blockIdx.x;
  const int sidx = (b & 7) * per + (b >> 3);
  const int mt = sidx / ntn;
  const int nt = sidx - mt * ntn;

  const u16* Ag = A + (size_t)(mt * 256) * K;
  const u16* Bg = Bw + (size_t)(nt * 256) * K;

  // staging geometry: per load-instr 512 thr x 16B = 64 rows x 128B
  const int srow = tid >> 3;                    // 0..63
  const int schunk = (tid & 7) ^ (srow & 7);    // pre-swizzled source chunk

#define STAGE_A(c, h)                                                          \
  do {                                                                         \
    const u16* _s = Ag + (size_t)((h) * 128 + srow) * K + ((c) << 6) + schunk * 8; \
    u16* _d = lds + (((c) & 1) << 15) + (h) * 8192 + tid * 8;                  \
    gload16(_s, _d);                                                           \
    gload16(_s + (size_t)64 * K, _d + 4096);                                   \
  } while (0)
#define STAGE_B(c, h)                                                          \
  do {                                                                         \
    const u16* _s = Bg + (size_t)((h) * 128 + srow) * K + ((c) << 6) + schunk * 8; \
    u16* _d = lds + (((c) & 1) << 15) + 16384 + (h) * 8192 + tid * 8;          \
    gload16(_s, _d);                                                           \
    gload16(_s + (size_t)64 * K, _d + 4096);                                   \
  } while (0)

  const int c0s = (kq ^ (lr & 7)) << 3;         // swizzled chunk offset, kk=0
  const int c1s = ((4 + kq) ^ (lr & 7)) << 3;   // kk=1
  const int aRowBase = (wm * 128 + lr) * 64;
  const int bRowBase = (wn * 64 + lr) * 64;

  short8 afr[4][2];      // current m-half fragments
  short8 bfr[2][2][2];   // [nh][ni][kk]
  f32x4 acc[8][4] = {};

  auto LDA = [&](int buf, int mh) {
    #pragma unroll
    for (int mi = 0; mi < 4; ++mi) {
      const u16* p = lds + (buf << 15) + aRowBase + (mh * 64 + mi * 16) * 64;
      afr[mi][0] = *(const short8*)(p + c0s);
      afr[mi][1] = *(const short8*)(p + c1s);
    }
  };
  auto LDB = [&](int buf, int nh) {
    #pragma unroll
    for (int ni = 0; ni < 2; ++ni) {
      const u16* p = lds + (buf << 15) + 16384 + bRowBase + ((nh * 2 + ni) * 16) * 64;
      bfr[nh][ni][0] = *(const short8*)(p + c0s);
      bfr[nh][ni][1] = *(const short8*)(p + c1s);
    }
  };
  auto MMA = [&](int mh, int nh) {
    __builtin_amdgcn_s_setprio(1);
    #pragma unroll
    for (int mi = 0; mi < 4; ++mi) {
      #pragma unroll
      for (int ni = 0; ni < 2; ++ni) {
        int m = mh * 4 + mi, n = nh * 2 + ni;
        acc[m][n] = __builtin_amdgcn_mfma_f32_16x16x32_bf16(afr[mi][0], bfr[nh][ni][0], acc[m][n], 0, 0, 0);
        acc[m][n] = __builtin_amdgcn_mfma_f32_16x16x32_bf16(afr[mi][1], bfr[nh][ni][1], acc[m][n], 0, 0, 0);
      }
    }
    __builtin_amdgcn_s_setprio(0);
  };

  // ---- prologue: stage K-tile 0 fully + B of K-tile 1 (FIFO: B0,A0,B1) ----
  STAGE_B(0, 0); STAGE_B(0, 1);
  STAGE_A(0, 0); STAGE_A(0, 1);
  STAGE_B(1, 0); STAGE_B(1, 1);
  asm volatile("s_waitcnt vmcnt(4)" ::: "memory");  // K-tile 0 landed
  BAR();

  const int NITER = K >> 7;   // 2 K-tiles (128 of K) per iteration
  for (int i = 0; i < NITER; ++i) {
    const int g = (i + 1 < NITER);
    const int cA = 2 * i + 1, c2 = 2 * i + 2, c3 = 2 * i + 3;

    // ---- K-tile 2i from buf0 ----
    // p0
    LDA(0, 0); LDB(0, 0);
    STAGE_A(cA, 0);
    BAR(); MMA(0, 0); BAR();
    // p1
    LDB(0, 1);
    STAGE_A(cA, 1);
    BAR(); MMA(0, 1); BAR();
    // p2
    LDA(0, 1);
    if (g) STAGE_B(c2, 0);
    BAR(); MMA(1, 1); BAR();
    // p3
    if (g) {
      STAGE_B(c2, 1);
      asm volatile("s_waitcnt vmcnt(4)" ::: "memory");
    } else {
      asm volatile("s_waitcnt vmcnt(0)" ::: "memory");
    }
    BAR(); MMA(1, 0); BAR();

    // ---- K-tile 2i+1 from buf1 ----
    // p4
    LDA(1, 0); LDB(1, 0);
    if (g) STAGE_A(c2, 0);
    BAR(); MMA(0, 0); BAR();
    // p5
    LDB(1, 1);
    if (g) STAGE_A(c2, 1);
    BAR(); MMA(0, 1); BAR();
    // p6
    LDA(1, 1);
    if (g) STAGE_B(c3, 0);
    BAR(); MMA(1, 1); BAR();
    // p7
    if (g) {
      STAGE_B(c3, 1);
      asm volatile("s_waitcnt vmcnt(4)" ::: "memory");
    }
    BAR(); MMA(1, 0); BAR();
  }
#undef STAGE_A
#undef STAGE_B

  // ---- epilogue ----
  const int rowB = mt * 256 + wm * 128 + kq * 4;
  const int colB = nt * 256 + wn * 64 + lr;
  #pragma unroll
  for (int m = 0; m < 8; ++m) {
    #pragma unroll
    for (int n = 0; n < 4; ++n) {
      #pragma unroll
      for (int j = 0; j < 4; ++j) {
        int row = rowB + m * 16 + j;
        int col = colB + n * 16;
        size_t idx = (size_t)row * N + col;
        float v = acc[m][n][j];
        if constexpr (MODE == 0) {
          ((u16*)Cptr)[idx] = f2bf(v);
        } else if constexpr (MODE == 1) {
          ((u16*)Cptr)[idx] = f2bf(1.0f / (1.0f + __expf(-v)));
        } else if constexpr (MODE == 2) {
          ((float*)Cptr)[idx] = v * bf2f(Gate[idx]);
        } else if constexpr (MODE == 3) {
          ((float*)Cptr)[idx] = 1.0f / (1.0f + __expf(-v));
        } else {
          float* O = (float*)Cptr;
          O[idx] = O[idx] * v;
        }
      }
    }
  }
}

// ---------------- K3: L2-normalize(q head) @ S[b,h] -> RMSNorm -> bf16 o_mid ----------------
__global__ __launch_bounds__(256) void glaread_k(const u16* __restrict__ q,
                                                 const float* __restrict__ S,
                                                 const float* __restrict__ vw,
                                                 u16* __restrict__ omid) {
  int bh = blockIdx.x;             // b*16 + h
  int b = bh >> 4, h = bh & 15;
  int tid = threadIdx.x;
  int w = tid >> 6, l = tid & 63;
  int lr = l & 15, kq = l >> 4;

  const float* Sp = S + (size_t)bh * HEADK * HEADV;
  short8 bfrag[8][2];
  #pragma unroll
  for (int n = 0; n < 8; ++n) {
    #pragma unroll
    for (int s = 0; s < 2; ++s) {
      #pragma unroll
      for (int i = 0; i < 8; ++i)
        bfrag[n][s][i] =
            (short)f2bf(Sp[(size_t)(s * 32 + kq * 8 + i) * HEADV + n * 16 + lr]);
    }
  }
  float vwn[8];
  #pragma unroll
  for (int n = 0; n < 8; ++n) vwn[n] = vw[n * 16 + lr];

  #pragma unroll 1
  for (int it = 0; it < 8; ++it) {
    int t0 = blockIdx.y * 512 + it * 64 + w * 16;
    const u16* qp = q + (size_t)(b * SEQ + t0 + lr) * KEYDIM + h * HEADK;
    short8 a0 = *(const short8*)(qp + kq * 8);
    short8 a1 = *(const short8*)(qp + 32 + kq * 8);

    float ss = 0.f;
    #pragma unroll
    for (int i = 0; i < 8; ++i) {
      float x0 = bf2f((u16)a0[i]), x1 = bf2f((u16)a1[i]);
      ss += x0 * x0 + x1 * x1;
    }
    ss += __shfl_xor(ss, 16);
    ss += __shfl_xor(ss, 32);
    float sc = 1.0f / fmaxf(sqrtf(ss), 1e-12f);

    short8 an0, an1;
    #pragma unroll
    for (int i = 0; i < 8; ++i) {
      an0[i] = (short)f2bf(bf2f((u16)a0[i]) * sc);
      an1[i] = (short)f2bf(bf2f((u16)a1[i]) * sc);
    }

    f32x4 acc[8] = {};
    #pragma unroll
    for (int n = 0; n < 8; ++n) {
      acc[n] = __builtin_amdgcn_mfma_f32_16x16x32_bf16(an0, bfrag[n][0], acc[n], 0, 0, 0);
      acc[n] = __builtin_amdgcn_mfma_f32_16x16x32_bf16(an1, bfrag[n][1], acc[n], 0, 0, 0);
    }

    float part[4] = {0.f, 0.f, 0.f, 0.f};
    #pragma unroll
    for (int n = 0; n < 8; ++n) {
      #pragma unroll
      for (int j = 0; j < 4; ++j) part[j] += acc[n][j] * acc[n][j];
    }
    #pragma unroll
    for (int msk = 1; msk <= 8; msk <<= 1) {
      #pragma unroll
      for (int j = 0; j < 4; ++j) part[j] += __shfl_xor(part[j], msk);
    }
    #pragma unroll
    for (int j = 0; j < 4; ++j) {
      float inv = rsqrtf(part[j] * (1.0f / HEADV) + 1e-5f);
      int tok = t0 + kq * 4 + j;
      u16* op = omid + (size_t)(b * SEQ + tok) * VALDIM + h * HEADV;
      #pragma unroll
      for (int n = 0; n < 8; ++n)
        op[n * 16 + lr] = f2bf(acc[n][j] * inv * vwn[n]);
    }
  }
}

extern "C" void kernel_launch(void* const* d_in, const int* in_sizes, int n_in,
                              void* d_out, int out_size, void* d_ws, size_t ws_size,
                              hipStream_t stream) {
  const float* hs = (const float*)d_in[0];   // (8,4096,2048)
  const float* S  = (const float*)d_in[1];   // (8,16,64,128)
  const float* nw = (const float*)d_in[2];   // (2048)
  const float* qw = (const float*)d_in[3];   // (1024,2048)
  const float* vw = (const float*)d_in[4];   // (128)
  const float* ow = (const float*)d_in[5];   // (2048,2048)
  const float* gw = (const float*)d_in[6];   // (2048,2048)
  float* out = (float*)d_out;

  u16* xb   = (u16*)d_ws;                             // NTOK*2048 bf16
  u16* q    = xb + (size_t)NTOK * HIDDEN;             // NTOK*1024 bf16
  u16* qwb  = q + (size_t)NTOK * KEYDIM;              // 1024*2048
  u16* owb  = qwb + (size_t)KEYDIM * HIDDEN;          // 2048*2048
  u16* gwb  = owb + (size_t)HIDDEN * VALDIM;          // 2048*2048
  u16* gatebuf = gwb + (size_t)HIDDEN * HIDDEN;       // NTOK*2048 bf16 (optional)
  u16* omid = xb;  // reuse xb after gate GEMM has consumed it

  const size_t need = ((size_t)NTOK * HIDDEN * 2) * 2 + (size_t)NTOK * KEYDIM * 2 +
                      ((size_t)KEYDIM * HIDDEN + 2 * (size_t)HIDDEN * HIDDEN) * 2;
  const bool bigws = ws_size >= need;

  const size_t LDSB = 131072;  // 128 KiB

  // weight casts
  cast_bf16_k<<<(KEYDIM * HIDDEN / 4 + 255) / 256, 256, 0, stream>>>(qw, qwb, KEYDIM * HIDDEN / 4);
  cast_bf16_k<<<(HIDDEN * VALDIM / 4 + 255) / 256, 256, 0, stream>>>(ow, owb, HIDDEN * VALDIM / 4);
  cast_bf16_k<<<(HIDDEN * HIDDEN / 4 + 255) / 256, 256, 0, stream>>>(gw, gwb, HIDDEN * HIDDEN / 4);

  // x = rmsnorm(hidden) -> bf16
  rmsnorm_cast_k<<<NTOK, 256, 0, stream>>>(hs, nw, xb);

  // q = x @ q_w^T  (bf16 out)
  gemm8p_k<0><<<dim3((NTOK / 256) * (KEYDIM / 256)), 512, LDSB, stream>>>(xb, qwb, q, nullptr, NTOK, KEYDIM, HIDDEN);

  // gate = sigmoid(x @ gate_w^T)
  if (bigws) {
    gemm8p_k<1><<<dim3((NTOK / 256) * (HIDDEN / 256)), 512, LDSB, stream>>>(xb, gwb, gatebuf, nullptr, NTOK, HIDDEN, HIDDEN);
  } else {
    gemm8p_k<3><<<dim3((NTOK / 256) * (HIDDEN / 256)), 512, LDSB, stream>>>(xb, gwb, out, nullptr, NTOK, HIDDEN, HIDDEN);
  }

  // o_mid = rmsnorm_v( l2norm(q_head) @ S[b,h] )  (bf16, overwrites xb)
  glaread_k<<<dim3(NBATCH * NHEADS, SEQ / 512), 256, 0, stream>>>(q, S, vw, omid);

  // out = (o_mid @ o_w^T) * gate
  if (bigws) {
    gemm8p_k<2><<<dim3((NTOK / 256) * (HIDDEN / 256)), 512, LDSB, stream>>>(omid, owb, out, gatebuf, NTOK, HIDDEN, VALDIM);
  } else {
    gemm8p_k<4><<<dim3((NTOK / 256) * (HIDDEN / 256)), 512, LDSB, stream>>>(omid, owb, out, nullptr, NTOK, HIDDEN, VALDIM);
  }
}

// Round 7
// 809.791 us; speedup vs baseline: 1.4085x; 1.0291x over previous
//
#include <hip/hip_runtime.h>

typedef unsigned short u16;
typedef unsigned int u32;
typedef __attribute__((ext_vector_type(4))) float f32x4;
typedef __attribute__((ext_vector_type(8))) short short8;
typedef __attribute__((ext_vector_type(4))) short short4v;

#define HIDDEN 2048
#define NHEADS 16
#define KEYDIM 1024
#define VALDIM 2048
#define HEADK 64
#define HEADV 128
#define NBATCH 8
#define SEQ 4096
#define NTOK (NBATCH * SEQ)

__device__ __forceinline__ u16 f2bf(float f) {
  union { float f; u32 u; } c; c.f = f;
  u32 r = c.u + 0x7FFFu + ((c.u >> 16) & 1u);
  return (u16)(r >> 16);
}
__device__ __forceinline__ float bf2f(u16 h) {
  union { u32 u; float f; } c; c.u = ((u32)h) << 16;
  return c.f;
}

// ---------------- weight cast f32 -> bf16 ----------------
__global__ __launch_bounds__(256) void cast_bf16_k(const float* __restrict__ in,
                                                   u16* __restrict__ out, int n4) {
  int i = blockIdx.x * blockDim.x + threadIdx.x;
  if (i >= n4) return;
  f32x4 v = *(const f32x4*)(in + (size_t)i * 4);
  short4v o;
  o[0] = (short)f2bf(v[0]); o[1] = (short)f2bf(v[1]);
  o[2] = (short)f2bf(v[2]); o[3] = (short)f2bf(v[3]);
  *(short4v*)(out + (size_t)i * 4) = o;
}

// ---------------- K1: RMSNorm(hidden) -> bf16 ----------------
__global__ __launch_bounds__(256) void rmsnorm_cast_k(const float* __restrict__ x,
                                                      const float* __restrict__ w,
                                                      u16* __restrict__ xb) {
  int r = blockIdx.x;
  int tid = threadIdx.x;
  const float* xp = x + (size_t)r * HIDDEN + tid * 8;
  f32x4 v0 = *(const f32x4*)xp;
  f32x4 v1 = *(const f32x4*)(xp + 4);
  float ss = v0[0]*v0[0]+v0[1]*v0[1]+v0[2]*v0[2]+v0[3]*v0[3]
           + v1[0]*v1[0]+v1[1]*v1[1]+v1[2]*v1[2]+v1[3]*v1[3];
  #pragma unroll
  for (int m = 32; m >= 1; m >>= 1) ss += __shfl_xor(ss, m);
  __shared__ float red[4];
  if ((tid & 63) == 0) red[tid >> 6] = ss;
  __syncthreads();
  float tot = red[0] + red[1] + red[2] + red[3];
  float inv = rsqrtf(tot * (1.0f / HIDDEN) + 1e-5f);
  const float* wp = w + tid * 8;
  f32x4 w0 = *(const f32x4*)wp;
  f32x4 w1 = *(const f32x4*)(wp + 4);
  short8 o;
  o[0] = (short)f2bf(v0[0] * inv * w0[0]);
  o[1] = (short)f2bf(v0[1] * inv * w0[1]);
  o[2] = (short)f2bf(v0[2] * inv * w0[2]);
  o[3] = (short)f2bf(v0[3] * inv * w0[3]);
  o[4] = (short)f2bf(v1[0] * inv * w1[0]);
  o[5] = (short)f2bf(v1[1] * inv * w1[1]);
  o[6] = (short)f2bf(v1[2] * inv * w1[2]);
  o[7] = (short)f2bf(v1[3] * inv * w1[3]);
  *(short8*)(xb + (size_t)r * HIDDEN + tid * 8) = o;
}

// ---------------- 256x256 GEMM, BK=64, ONE barrier per phase ----------------
// C[M,N] = A[M,K] @ B[N,K]^T, bf16 in.
// MODE 0: bf16 store.  1: sigmoid bf16.  2: f32 = acc*bf2f(Gate).  3: sigmoid f32.  4: f32 RMW.
// Phase = { ds_reads ; 1 half-tile stage ; [vmcnt @p3/p7] ; s_barrier ; 16 MFMA }.
// Single-barrier hazard rule (derived): stage in region p may target a slot whose last
// ds_read was CONSUMED by an MFMA in region <= p-1 (consumption precedes that wave's
// BAR_{p-1} arrival, which precedes any wave's region-p stage issue).  To give B slots
// gap-2, ALL B fragments are ds_read at phase 0 of each K-tile (same regs: bfr holds
// all 4 n-frags).  Slot freedom: B buf0 @p2, A buf0 @p4, B buf1 @p6, A buf1 @p0.
// Stages: A(2i+1)@p0,p1  B(2i+2)@p2,p3  A(2i+2)@p4,p5  B(2i+3)@p6,p7.
// vmcnt(4)@p3 retires [B(2i+1),A(2i+1)] (issued >=2 phases ago); vmcnt(4)@p7 retires
// [B(2i+2),A(2i+2)].  No sched_barrier anywhere (m141: keep the scheduler free).

__device__ __forceinline__ void gload16(const u16* g, u16* l) {
  __builtin_amdgcn_global_load_lds((const __attribute__((address_space(1))) void*)g,
                                   (__attribute__((address_space(3))) void*)l, 16, 0, 0);
}

#define BAR()                                  \
  do {                                         \
    asm volatile("" ::: "memory");             \
    __builtin_amdgcn_s_barrier();              \
    asm volatile("" ::: "memory");             \
  } while (0)

template <int MODE>
__global__ __launch_bounds__(512, 2) void gemm1b_k(const u16* __restrict__ A,
                                                   const u16* __restrict__ Bw,
                                                   void* __restrict__ Cptr,
                                                   const u16* __restrict__ Gate,
                                                   int M, int N, int K) {
  extern __shared__ u16 lds[];
  const int tid = threadIdx.x;
  const int wid = tid >> 6;
  const int wm = wid >> 2;          // 0..1  (M half)
  const int wn = wid & 3;           // 0..3  (N quarter)
  const int l = tid & 63;
  const int lr = l & 15;
  const int kq = l >> 4;

  // XCD-aware swizzle + N-tile-fastest
  const int ntn = N >> 8;
  const int per = gridDim.x >> 3;
  const int b = blockIdx.x;
  const int sidx = (b & 7) * per + (b >> 3);
  const int mt = sidx / ntn;
  const int nt = sidx - mt * ntn;

  const u16* Ag = A + (size_t)(mt * 256) * K;
  const u16* Bg = Bw + (size_t)(nt * 256) * K;

  // staging geometry: per load-instr 512 thr x 16B = 64 rows x 128B
  const int srow = tid >> 3;                    // 0..63
  const int schunk = (tid & 7) ^ (srow & 7);    // pre-swizzled source chunk

#define STAGE_A(c, h)                                                          \
  do {                                                                         \
    const u16* _s = Ag + (size_t)((h) * 128 + srow) * K + ((c) << 6) + schunk * 8; \
    u16* _d = lds + (((c) & 1) << 15) + (h) * 8192 + tid * 8;                  \
    gload16(_s, _d);                                                           \
    gload16(_s + (size_t)64 * K, _d + 4096);                                   \
  } while (0)
#define STAGE_B(c, h)                                                          \
  do {                                                                         \
    const u16* _s = Bg + (size_t)((h) * 128 + srow) * K + ((c) << 6) + schunk * 8; \
    u16* _d = lds + (((c) & 1) << 15) + 16384 + (h) * 8192 + tid * 8;          \
    gload16(_s, _d);                                                           \
    gload16(_s + (size_t)64 * K, _d + 4096);                                   \
  } while (0)

  const int c0s = (kq ^ (lr & 7)) << 3;         // swizzled chunk offset, kk=0
  const int c1s = ((4 + kq) ^ (lr & 7)) << 3;   // kk=1
  const int aRowBase = (wm * 128 + lr) * 64;
  const int bRowBase = (wn * 64 + lr) * 64;

  short8 afr[4][2];      // current m-half fragments
  short8 bfr[2][2][2];   // [nh][ni][kk] — full B tile for this wave
  f32x4 acc[8][4] = {};

  auto LDA = [&](int buf, int mh) {
    #pragma unroll
    for (int mi = 0; mi < 4; ++mi) {
      const u16* p = lds + (buf << 15) + aRowBase + (mh * 64 + mi * 16) * 64;
      afr[mi][0] = *(const short8*)(p + c0s);
      afr[mi][1] = *(const short8*)(p + c1s);
    }
  };
  auto LDB_ALL = [&](int buf) {
    #pragma unroll
    for (int nh = 0; nh < 2; ++nh) {
      #pragma unroll
      for (int ni = 0; ni < 2; ++ni) {
        const u16* p = lds + (buf << 15) + 16384 + bRowBase + ((nh * 2 + ni) * 16) * 64;
        bfr[nh][ni][0] = *(const short8*)(p + c0s);
        bfr[nh][ni][1] = *(const short8*)(p + c1s);
      }
    }
  };
  auto MMA = [&](int mh, int nh) {
    __builtin_amdgcn_s_setprio(1);
    #pragma unroll
    for (int mi = 0; mi < 4; ++mi) {
      #pragma unroll
      for (int ni = 0; ni < 2; ++ni) {
        int m = mh * 4 + mi, n = nh * 2 + ni;
        acc[m][n] = __builtin_amdgcn_mfma_f32_16x16x32_bf16(afr[mi][0], bfr[nh][ni][0], acc[m][n], 0, 0, 0);
        acc[m][n] = __builtin_amdgcn_mfma_f32_16x16x32_bf16(afr[mi][1], bfr[nh][ni][1], acc[m][n], 0, 0, 0);
      }
    }
    __builtin_amdgcn_s_setprio(0);
  };

  // ---- prologue: FIFO A(0) B(0) B(1); vmcnt(4) keeps B(1) in flight ----
  STAGE_A(0, 0); STAGE_A(0, 1);
  STAGE_B(0, 0); STAGE_B(0, 1);
  STAGE_B(1, 0); STAGE_B(1, 1);
  asm volatile("s_waitcnt vmcnt(4)" ::: "memory");  // A(0),B(0) landed
  BAR();

  const int NITER = K >> 7;   // 2 K-tiles (128 of K) per iteration
  for (int i = 0; i < NITER; ++i) {
    const int g = (i + 1 < NITER);
    const int cA = 2 * i + 1, c2 = 2 * i + 2, c3 = 2 * i + 3;

    // ---- K-tile 2i (buf0) ----
    // p0
    LDB_ALL(0); LDA(0, 0);
    STAGE_A(cA, 0);
    BAR(); MMA(0, 0);
    // p1
    STAGE_A(cA, 1);
    BAR(); MMA(0, 1);
    // p2
    LDA(0, 1);
    if (g) STAGE_B(c2, 0);
    BAR(); MMA(1, 1);
    // p3
    if (g) {
      STAGE_B(c2, 1);
      asm volatile("s_waitcnt vmcnt(4)" ::: "memory");
    } else {
      asm volatile("s_waitcnt vmcnt(0)" ::: "memory");
    }
    BAR(); MMA(1, 0);

    // ---- K-tile 2i+1 (buf1) ----
    // p4
    LDB_ALL(1); LDA(1, 0);
    if (g) STAGE_A(c2, 0);
    BAR(); MMA(0, 0);
    // p5
    if (g) STAGE_A(c2, 1);
    BAR(); MMA(0, 1);
    // p6
    LDA(1, 1);
    if (g) STAGE_B(c3, 0);
    BAR(); MMA(1, 1);
    // p7
    if (g) {
      STAGE_B(c3, 1);
      asm volatile("s_waitcnt vmcnt(4)" ::: "memory");
    }
    BAR(); MMA(1, 0);
  }
#undef STAGE_A
#undef STAGE_B

  // ---- epilogue ----
  const int rowB = mt * 256 + wm * 128 + kq * 4;
  const int colB = nt * 256 + wn * 64 + lr;
  #pragma unroll
  for (int m = 0; m < 8; ++m) {
    #pragma unroll
    for (int n = 0; n < 4; ++n) {
      #pragma unroll
      for (int j = 0; j < 4; ++j) {
        int row = rowB + m * 16 + j;
        int col = colB + n * 16;
        size_t idx = (size_t)row * N + col;
        float v = acc[m][n][j];
        if constexpr (MODE == 0) {
          ((u16*)Cptr)[idx] = f2bf(v);
        } else if constexpr (MODE == 1) {
          ((u16*)Cptr)[idx] = f2bf(1.0f / (1.0f + __expf(-v)));
        } else if constexpr (MODE == 2) {
          ((float*)Cptr)[idx] = v * bf2f(Gate[idx]);
        } else if constexpr (MODE == 3) {
          ((float*)Cptr)[idx] = 1.0f / (1.0f + __expf(-v));
        } else {
          float* O = (float*)Cptr;
          O[idx] = O[idx] * v;
        }
      }
    }
  }
}

// ---------------- K3: L2-normalize(q head) @ S[b,h] -> RMSNorm -> bf16 o_mid ----------------
__global__ __launch_bounds__(256) void glaread_k(const u16* __restrict__ q,
                                                 const float* __restrict__ S,
                                                 const float* __restrict__ vw,
                                                 u16* __restrict__ omid) {
  int bh = blockIdx.x;             // b*16 + h
  int b = bh >> 4, h = bh & 15;
  int tid = threadIdx.x;
  int w = tid >> 6, l = tid & 63;
  int lr = l & 15, kq = l >> 4;

  const float* Sp = S + (size_t)bh * HEADK * HEADV;
  short8 bfrag[8][2];
  #pragma unroll
  for (int n = 0; n < 8; ++n) {
    #pragma unroll
    for (int s = 0; s < 2; ++s) {
      #pragma unroll
      for (int i = 0; i < 8; ++i)
        bfrag[n][s][i] =
            (short)f2bf(Sp[(size_t)(s * 32 + kq * 8 + i) * HEADV + n * 16 + lr]);
    }
  }
  float vwn[8];
  #pragma unroll
  for (int n = 0; n < 8; ++n) vwn[n] = vw[n * 16 + lr];

  #pragma unroll 1
  for (int it = 0; it < 8; ++it) {
    int t0 = blockIdx.y * 512 + it * 64 + w * 16;
    const u16* qp = q + (size_t)(b * SEQ + t0 + lr) * KEYDIM + h * HEADK;
    short8 a0 = *(const short8*)(qp + kq * 8);
    short8 a1 = *(const short8*)(qp + 32 + kq * 8);

    float ss = 0.f;
    #pragma unroll
    for (int i = 0; i < 8; ++i) {
      float x0 = bf2f((u16)a0[i]), x1 = bf2f((u16)a1[i]);
      ss += x0 * x0 + x1 * x1;
    }
    ss += __shfl_xor(ss, 16);
    ss += __shfl_xor(ss, 32);
    float sc = 1.0f / fmaxf(sqrtf(ss), 1e-12f);

    short8 an0, an1;
    #pragma unroll
    for (int i = 0; i < 8; ++i) {
      an0[i] = (short)f2bf(bf2f((u16)a0[i]) * sc);
      an1[i] = (short)f2bf(bf2f((u16)a1[i]) * sc);
    }

    f32x4 acc[8] = {};
    #pragma unroll
    for (int n = 0; n < 8; ++n) {
      acc[n] = __builtin_amdgcn_mfma_f32_16x16x32_bf16(an0, bfrag[n][0], acc[n], 0, 0, 0);
      acc[n] = __builtin_amdgcn_mfma_f32_16x16x32_bf16(an1, bfrag[n][1], acc[n], 0, 0, 0);
    }

    float part[4] = {0.f, 0.f, 0.f, 0.f};
    #pragma unroll
    for (int n = 0; n < 8; ++n) {
      #pragma unroll
      for (int j = 0; j < 4; ++j) part[j] += acc[n][j] * acc[n][j];
    }
    #pragma unroll
    for (int msk = 1; msk <= 8; msk <<= 1) {
      #pragma unroll
      for (int j = 0; j < 4; ++j) part[j] += __shfl_xor(part[j], msk);
    }
    #pragma unroll
    for (int j = 0; j < 4; ++j) {
      float inv = rsqrtf(part[j] * (1.0f / HEADV) + 1e-5f);
      int tok = t0 + kq * 4 + j;
      u16* op = omid + (size_t)(b * SEQ + tok) * VALDIM + h * HEADV;
      #pragma unroll
      for (int n = 0; n < 8; ++n)
        op[n * 16 + lr] = f2bf(acc[n][j] * inv * vwn[n]);
    }
  }
}

extern "C" void kernel_launch(void* const* d_in, const int* in_sizes, int n_in,
                              void* d_out, int out_size, void* d_ws, size_t ws_size,
                              hipStream_t stream) {
  const float* hs = (const float*)d_in[0];   // (8,4096,2048)
  const float* S  = (const float*)d_in[1];   // (8,16,64,128)
  const float* nw = (const float*)d_in[2];   // (2048)
  const float* qw = (const float*)d_in[3];   // (1024,2048)
  const float* vw = (const float*)d_in[4];   // (128)
  const float* ow = (const float*)d_in[5];   // (2048,2048)
  const float* gw = (const float*)d_in[6];   // (2048,2048)
  float* out = (float*)d_out;

  u16* xb   = (u16*)d_ws;                             // NTOK*2048 bf16
  u16* q    = xb + (size_t)NTOK * HIDDEN;             // NTOK*1024 bf16
  u16* qwb  = q + (size_t)NTOK * KEYDIM;              // 1024*2048
  u16* owb  = qwb + (size_t)KEYDIM * HIDDEN;          // 2048*2048
  u16* gwb  = owb + (size_t)HIDDEN * VALDIM;          // 2048*2048
  u16* gatebuf = gwb + (size_t)HIDDEN * HIDDEN;       // NTOK*2048 bf16 (optional)
  u16* omid = xb;  // reuse xb after gate GEMM has consumed it

  const size_t need = ((size_t)NTOK * HIDDEN * 2) * 2 + (size_t)NTOK * KEYDIM * 2 +
                      ((size_t)KEYDIM * HIDDEN + 2 * (size_t)HIDDEN * HIDDEN) * 2;
  const bool bigws = ws_size >= need;

  const size_t LDSB = 131072;  // 128 KiB

  // weight casts
  cast_bf16_k<<<(KEYDIM * HIDDEN / 4 + 255) / 256, 256, 0, stream>>>(qw, qwb, KEYDIM * HIDDEN / 4);
  cast_bf16_k<<<(HIDDEN * VALDIM / 4 + 255) / 256, 256, 0, stream>>>(ow, owb, HIDDEN * VALDIM / 4);
  cast_bf16_k<<<(HIDDEN * HIDDEN / 4 + 255) / 256, 256, 0, stream>>>(gw, gwb, HIDDEN * HIDDEN / 4);

  // x = rmsnorm(hidden) -> bf16
  rmsnorm_cast_k<<<NTOK, 256, 0, stream>>>(hs, nw, xb);

  // q = x @ q_w^T  (bf16 out)
  gemm1b_k<0><<<dim3((NTOK / 256) * (KEYDIM / 256)), 512, LDSB, stream>>>(xb, qwb, q, nullptr, NTOK, KEYDIM, HIDDEN);

  // gate = sigmoid(x @ gate_w^T)
  if (bigws) {
    gemm1b_k<1><<<dim3((NTOK / 256) * (HIDDEN / 256)), 512, LDSB, stream>>>(xb, gwb, gatebuf, nullptr, NTOK, HIDDEN, HIDDEN);
  } else {
    gemm1b_k<3><<<dim3((NTOK / 256) * (HIDDEN / 256)), 512, LDSB, stream>>>(xb, gwb, out, nullptr, NTOK, HIDDEN, HIDDEN);
  }

  // o_mid = rmsnorm_v( l2norm(q_head) @ S[b,h] )  (bf16, overwrites xb)
  glaread_k<<<dim3(NBATCH * NHEADS, SEQ / 512), 256, 0, stream>>>(q, S, vw, omid);

  // out = (o_mid @ o_w^T) * gate
  if (bigws) {
    gemm1b_k<2><<<dim3((NTOK / 256) * (HIDDEN / 256)), 512, LDSB, stream>>>(omid, owb, out, gatebuf, NTOK, HIDDEN, VALDIM);
  } else {
    gemm1b_k<4><<<dim3((NTOK / 256) * (HIDDEN / 256)), 512, LDSB, stream>>>(omid, owb, out, nullptr, NTOK, HIDDEN, VALDIM);
  }
}